// Round 4
// baseline (149.511 us; speedup 1.0000x reference)
//
#include <hip/hip_runtime.h>

// CrossNetLayer, 2 dispatches.
//   prep:       W fp32[k][n] -> Wt f16[n][k]; x fp32 -> xh f16;
//               crossnet constants c[4], beta4[1024]; zero slab counters.
//   gemm+cross: h = xh @ Wt^T + b_enc (64x64 tile, BK=128, 8 waves);
//               last block per 64-row slab (atomic counter) runs the
//               affine-collapsed crossnet tail for its rows in-place.
// R6: dispatch-count experiment 3 -> 2 (crossnet fused as last-block tail).
// GEMM internals byte-identical to verified R5; b_enc folded into epilogue.

#define B_SZ 1024
#define D_SZ 1024
#define H_SZ 1024
#define DEPTH 4

typedef _Float16 half4_t __attribute__((ext_vector_type(4)));
typedef _Float16 half8_t __attribute__((ext_vector_type(8)));
typedef float floatx4_t __attribute__((ext_vector_type(4)));

typedef const __attribute__((address_space(1))) unsigned int* gas_ptr;
typedef __attribute__((address_space(3))) unsigned int* las_ptr;

__device__ __forceinline__ void async_copy16(const void* g, void* l) {
    // 16 B per lane; HW dest = wave-uniform base + lane*16
    __builtin_amdgcn_global_load_lds((gas_ptr)g, (las_ptr)l, 16, 0, 0);
}

// ---------------------------------------------------------------------------
// Kernel 1: prep. Blocks 0..255: transpose-convert W; 256..511: convert x;
// block 512: crossnet constants c_l = (sum_{j<l} b_j) . w_l, beta4, cnt=0.
// ---------------------------------------------------------------------------
__global__ __launch_bounds__(256) void prep_kernel(
        const float* __restrict__ x, const float* __restrict__ W,
        const float* __restrict__ ws, const float* __restrict__ bs,
        _Float16* __restrict__ xh, _Float16* __restrict__ Wt,
        float* __restrict__ cvec, float* __restrict__ beta4,
        int* __restrict__ cnt) {
    const int b = blockIdx.x;
    const int t = threadIdx.x;
    if (b < 256) {
        __shared__ float S[64][65];    // +1 pad: transposed reads conflict-free
        const int k0 = (b >> 4) << 6;
        const int n0 = (b & 15) << 6;
#pragma unroll
        for (int i = 0; i < 4; ++i) {
            int idx = (i << 8) + t;
            int r = idx >> 4;              // k-local 0..63
            int c4 = idx & 15;             // float4 group along n
            float4 v = *(const float4*)(W + (size_t)(k0 + r) * H_SZ + n0 + (c4 << 2));
            S[r][(c4 << 2) + 0] = v.x;
            S[r][(c4 << 2) + 1] = v.y;
            S[r][(c4 << 2) + 2] = v.z;
            S[r][(c4 << 2) + 3] = v.w;
        }
        __syncthreads();
#pragma unroll
        for (int i = 0; i < 4; ++i) {
            int idx = (i << 8) + t;
            int n = idx >> 4;              // n-local 0..63
            int c4 = idx & 15;
            int k = c4 << 2;
            half4_t o;
            o.x = (_Float16)S[k + 0][n];
            o.y = (_Float16)S[k + 1][n];
            o.z = (_Float16)S[k + 2][n];
            o.w = (_Float16)S[k + 3][n];
            *(half4_t*)(Wt + (size_t)(n0 + n) * D_SZ + k0 + k) = o;
        }
    } else if (b < 512) {
        const int base = (b - 256) * 4096;
#pragma unroll
        for (int i = 0; i < 4; ++i) {
            int off = base + (((i << 8) + t) << 2);
            float4 v = *(const float4*)(x + off);
            half4_t o;
            o.x = (_Float16)v.x; o.y = (_Float16)v.y;
            o.z = (_Float16)v.z; o.w = (_Float16)v.w;
            *(half4_t*)(xh + off) = o;
        }
    } else {
        // crossnet constants + counter zeroing (runs before gemm, same stream)
        if (t < 16) cnt[t] = 0;
        __shared__ float redc[4][3];
        const int j = t << 2;
        float4 b0 = *(const float4*)(bs + 0 * H_SZ + j);
        float4 b1 = *(const float4*)(bs + 1 * H_SZ + j);
        float4 b2 = *(const float4*)(bs + 2 * H_SZ + j);
        float4 b3 = *(const float4*)(bs + 3 * H_SZ + j);
        float4 w1 = *(const float4*)(ws + 1 * H_SZ + j);
        float4 w2 = *(const float4*)(ws + 2 * H_SZ + j);
        float4 w3 = *(const float4*)(ws + 3 * H_SZ + j);
        float4 pre1 = b0;
        float4 pre2 = {pre1.x + b1.x, pre1.y + b1.y, pre1.z + b1.z, pre1.w + b1.w};
        float4 pre3 = {pre2.x + b2.x, pre2.y + b2.y, pre2.z + b2.z, pre2.w + b2.w};
        float4 bt   = {pre3.x + b3.x, pre3.y + b3.y, pre3.z + b3.z, pre3.w + b3.w};
        *(float4*)(beta4 + j) = bt;
        float pp[3];
        pp[0] = pre1.x * w1.x + pre1.y * w1.y + pre1.z * w1.z + pre1.w * w1.w;
        pp[1] = pre2.x * w2.x + pre2.y * w2.y + pre2.z * w2.z + pre2.w * w2.w;
        pp[2] = pre3.x * w3.x + pre3.y * w3.y + pre3.z * w3.z + pre3.w * w3.w;
#pragma unroll
        for (int off = 32; off > 0; off >>= 1) {
#pragma unroll
            for (int l = 0; l < 3; ++l) pp[l] += __shfl_down(pp[l], off, 64);
        }
        if ((t & 63) == 0) {
#pragma unroll
            for (int l = 0; l < 3; ++l) redc[t >> 6][l] = pp[l];
        }
        __syncthreads();
        if (t == 0) {
            cvec[0] = 0.0f;
#pragma unroll
            for (int l = 0; l < 3; ++l)
                cvec[l + 1] = redc[0][l] + redc[1][l] + redc[2][l] + redc[3][l];
        }
    }
}

// ---------------------------------------------------------------------------
// Kernel 2: GEMM h = xh @ Wt^T + b_enc, then last-block crossnet tail.
// BM=64, BN=64, BK=128. 512 thr = 8 waves in 2(m) x 4(n); each wave 32x16.
// grid (16,16) = 256 blocks. Double-buffered swizzled LDS (64 KB).
// ---------------------------------------------------------------------------
__global__ __launch_bounds__(512, 2) void gemm_cross_kernel(
        const _Float16* __restrict__ xh, const _Float16* __restrict__ Wt,
        const float* __restrict__ b_enc, const float* __restrict__ ws,
        const float* __restrict__ cvec, const float* __restrict__ beta4,
        float* __restrict__ h, int* __restrict__ cnt) {
    __shared__ _Float16 As[2][64 * 128];   // 16 KB / buf
    __shared__ _Float16 Bs[2][64 * 128];   // 16 KB / buf
    __shared__ int lastFlag;
    const int tid  = threadIdx.x;
    const int lane = tid & 63;
    const int w    = tid >> 6;            // 0..7
    const int m0 = blockIdx.y << 6;
    const int n0 = blockIdx.x << 6;
    const int wm = (w >> 2) << 5;         // 0 / 32
    const int wn = (w & 3) << 4;          // 0 / 16 / 32 / 48

    // staging: 1024 slots per matrix, 2 per thread (t and t+512).
    // slot s -> row r = s>>4, phys chunk s&15, logical chunk (s&15)^(r&15).
    const int r0 = tid >> 4;
    const int c0 = ((tid & 15) ^ (r0 & 15)) << 3;
    const int r1 = r0 + 32;
    const int c1 = ((tid & 15) ^ (r1 & 15)) << 3;
    const _Float16* aSrc0 = xh + (size_t)(m0 + r0) * D_SZ + c0;
    const _Float16* aSrc1 = xh + (size_t)(m0 + r1) * D_SZ + c1;
    const _Float16* bSrc0 = Wt + (size_t)(n0 + r0) * D_SZ + c0;
    const _Float16* bSrc1 = Wt + (size_t)(n0 + r1) * D_SZ + c1;

    // fragment geometry (16x16x32): A[m=lane&15][k=q*8+j], B symmetric.
    const int ra = wm + (lane & 15);      // m-frag 0 row; frag 1 = ra+16
    const int rb = wn + (lane & 15);
    const int q  = lane >> 4;

    floatx4_t acc0 = {0.0f, 0.0f, 0.0f, 0.0f};
    floatx4_t acc1 = {0.0f, 0.0f, 0.0f, 0.0f};

    async_copy16(aSrc0, &As[0][tid << 3]);
    async_copy16(aSrc1, &As[0][(tid + 512) << 3]);
    async_copy16(bSrc0, &Bs[0][tid << 3]);
    async_copy16(bSrc1, &Bs[0][(tid + 512) << 3]);

    for (int it = 0; it < 8; ++it) {
        __syncthreads();   // drains stage(it); all waves done reading buf[(it+1)&1]
        if (it + 1 < 8) {
            int k0 = (it + 1) << 7;
            int buf = (it + 1) & 1;
            async_copy16(aSrc0 + k0, &As[buf][tid << 3]);
            async_copy16(aSrc1 + k0, &As[buf][(tid + 512) << 3]);
            async_copy16(bSrc0 + k0, &Bs[buf][tid << 3]);
            async_copy16(bSrc1 + k0, &Bs[buf][(tid + 512) << 3]);
        }
        const _Float16* Ab = As[it & 1];
        const _Float16* Bb = Bs[it & 1];
#pragma unroll
        for (int kk = 0; kk < 4; ++kk) {
            int l = (kk << 2) + q;
            int swz = (l ^ (ra & 15)) << 3;     // same for ra and ra+16
            half8_t bf = *(const half8_t*)(Bb + rb * 128 + ((l ^ (rb & 15)) << 3));
            half8_t a0 = *(const half8_t*)(Ab + ra * 128 + swz);
            half8_t a1 = *(const half8_t*)(Ab + (ra + 16) * 128 + swz);
            acc0 = __builtin_amdgcn_mfma_f32_16x16x32_f16(a0, bf, acc0, 0, 0, 0);
            acc1 = __builtin_amdgcn_mfma_f32_16x16x32_f16(a1, bf, acc1, 0, 0, 0);
        }
    }

    // C/D: col = lane&15, row = (lane>>4)*4 + reg. b_enc folded in here.
    const int col  = n0 + wn + (lane & 15);
    const int row0 = m0 + wm + (q << 2);
    const float be = b_enc[col];
#pragma unroll
    for (int r = 0; r < 4; ++r) {
        h[(size_t)(row0 + r) * H_SZ + col] = acc0[r] + be;
        h[(size_t)(row0 + 16 + r) * H_SZ + col] = acc1[r] + be;
    }

    // ---- last-block election for this 64-row slab (blockIdx.y) ----
    __threadfence();                       // release: tile stores device-visible
    __syncthreads();                       // all threads' stores+fences done
    if (tid == 0) lastFlag = (atomicAdd(&cnt[blockIdx.y], 1) == 15);
    __syncthreads();
    if (!lastFlag) return;
    __threadfence();                       // acquire: no stale h lines

    // ---- crossnet tail (affine-collapsed): rows m0..m0+63, wave = 8 rows ----
    // x0 = h row (b_enc already folded in);  d_l = x0 . w_l;
    // sig: s_l = sig*d_l + c_l, sig += s_l;  out = sig*x0 + beta4.
    const int lc = lane << 2;
    float4 wv[DEPTH][4];
    float4 bt[4];
#pragma unroll
    for (int l = 0; l < DEPTH; ++l)
#pragma unroll
        for (int i = 0; i < 4; ++i)
            wv[l][i] = *(const float4*)(ws + l * H_SZ + (i << 8) + lc);
#pragma unroll
    for (int i = 0; i < 4; ++i)
        bt[i] = *(const float4*)(beta4 + (i << 8) + lc);
    const float4 cv = *(const float4*)cvec;
    const float cvl[4] = {cv.x, cv.y, cv.z, cv.w};

    for (int rr = 0; rr < 8; ++rr) {
        float* hr = h + (size_t)(m0 + (w << 3) + rr) * H_SZ;
        float4 xv[4];
#pragma unroll
        for (int i = 0; i < 4; ++i) xv[i] = *(const float4*)(hr + (i << 8) + lc);
        float p[DEPTH] = {0.f, 0.f, 0.f, 0.f};
#pragma unroll
        for (int l = 0; l < DEPTH; ++l)
#pragma unroll
            for (int i = 0; i < 4; ++i)
                p[l] += xv[i].x * wv[l][i].x + xv[i].y * wv[l][i].y +
                        xv[i].z * wv[l][i].z + xv[i].w * wv[l][i].w;
#pragma unroll
        for (int off = 32; off > 0; off >>= 1) {
#pragma unroll
            for (int l = 0; l < DEPTH; ++l) p[l] += __shfl_xor(p[l], off, 64);
        }
        float sig = 1.0f;
#pragma unroll
        for (int l = 0; l < DEPTH; ++l) {
            float s = sig * p[l] + cvl[l];
            sig += s;
        }
#pragma unroll
        for (int i = 0; i < 4; ++i) {
            float4 o = {xv[i].x * sig + bt[i].x, xv[i].y * sig + bt[i].y,
                        xv[i].z * sig + bt[i].z, xv[i].w * sig + bt[i].w};
            *(float4*)(hr + (i << 8) + lc) = o;
        }
    }
}

extern "C" void kernel_launch(void* const* d_in, const int* in_sizes, int n_in,
                              void* d_out, int out_size, void* d_ws, size_t ws_size,
                              hipStream_t stream) {
    const float* x     = (const float*)d_in[0];
    const float* W_enc = (const float*)d_in[1];
    const float* b_enc = (const float*)d_in[2];
    const float* ws    = (const float*)d_in[3];
    const float* bs    = (const float*)d_in[4];
    float* out = (float*)d_out;

    _Float16* xh = (_Float16*)d_ws;                 // 2 MB
    _Float16* Wt = xh + (size_t)B_SZ * D_SZ;        // 2 MB
    float* aux   = (float*)((char*)d_ws + 4u * 1024u * 1024u);
    float* cvec  = aux;                             // 4 floats
    float* beta4 = aux + 4;                         // 1024 floats (16B-aligned)
    int*   cnt   = (int*)(aux + 4 + H_SZ);          // 16 ints, zeroed by prep

    prep_kernel<<<513, 256, 0, stream>>>(x, W_enc, ws, bs, xh, Wt, cvec, beta4, cnt);
    dim3 grid(H_SZ / 64, B_SZ / 64);                // (n-tiles, m-tiles)
    gemm_cross_kernel<<<grid, 512, 0, stream>>>(xh, Wt, b_enc, ws, cvec, beta4,
                                                out, cnt);
}

// Round 5
// 79.981 us; speedup vs baseline: 1.8693x; 1.8693x over previous
//
#include <hip/hip_runtime.h>

// CrossNetLayer, 3 dispatches.
//   prep:     W fp32[k][n] -> Wt f16[n][k]; x fp32 -> xh f16;
//             crossnet constants c[4], beta4[1024] (affine collapse).
//   gemm:     h = xh @ Wt^T + b_enc. BM=32 BN=64 BK=128, 8 waves,
//             grid 512 = 2 blocks/CU (latency overlap), dbuf swizzled LDS.
//   crossnet: out = sigma*x0 + beta4 (single-pass affine-collapsed).
// R7: reverted R6's last-block fence/atomic tail (gemm_cross was 88us with
// ~1% util -> device-scope fences per block are us-scale on gfx950).
// GEMM re-gridded for 2 blocks/CU; b_enc stays folded into the epilogue.

#define B_SZ 1024
#define D_SZ 1024
#define H_SZ 1024
#define DEPTH 4

typedef _Float16 half4_t __attribute__((ext_vector_type(4)));
typedef _Float16 half8_t __attribute__((ext_vector_type(8)));
typedef float floatx4_t __attribute__((ext_vector_type(4)));

typedef const __attribute__((address_space(1))) unsigned int* gas_ptr;
typedef __attribute__((address_space(3))) unsigned int* las_ptr;

__device__ __forceinline__ void async_copy16(const void* g, void* l) {
    // 16 B per lane; HW dest = wave-uniform base + lane*16
    __builtin_amdgcn_global_load_lds((gas_ptr)g, (las_ptr)l, 16, 0, 0);
}

// ---------------------------------------------------------------------------
// Kernel 1: prep. Blocks 0..255: transpose-convert W; 256..511: convert x;
// block 512: crossnet constants c_l = (sum_{j<l} b_j) . w_l and beta4.
// ---------------------------------------------------------------------------
__global__ __launch_bounds__(256) void prep_kernel(
        const float* __restrict__ x, const float* __restrict__ W,
        const float* __restrict__ ws, const float* __restrict__ bs,
        _Float16* __restrict__ xh, _Float16* __restrict__ Wt,
        float* __restrict__ cvec, float* __restrict__ beta4) {
    const int b = blockIdx.x;
    const int t = threadIdx.x;
    if (b < 256) {
        __shared__ float S[64][65];    // +1 pad: transposed reads conflict-free
        const int k0 = (b >> 4) << 6;
        const int n0 = (b & 15) << 6;
#pragma unroll
        for (int i = 0; i < 4; ++i) {
            int idx = (i << 8) + t;
            int r = idx >> 4;              // k-local 0..63
            int c4 = idx & 15;             // float4 group along n
            float4 v = *(const float4*)(W + (size_t)(k0 + r) * H_SZ + n0 + (c4 << 2));
            S[r][(c4 << 2) + 0] = v.x;
            S[r][(c4 << 2) + 1] = v.y;
            S[r][(c4 << 2) + 2] = v.z;
            S[r][(c4 << 2) + 3] = v.w;
        }
        __syncthreads();
#pragma unroll
        for (int i = 0; i < 4; ++i) {
            int idx = (i << 8) + t;
            int n = idx >> 4;              // n-local 0..63
            int c4 = idx & 15;
            int k = c4 << 2;
            half4_t o;
            o.x = (_Float16)S[k + 0][n];
            o.y = (_Float16)S[k + 1][n];
            o.z = (_Float16)S[k + 2][n];
            o.w = (_Float16)S[k + 3][n];
            *(half4_t*)(Wt + (size_t)(n0 + n) * D_SZ + k0 + k) = o;
        }
    } else if (b < 512) {
        const int base = (b - 256) * 4096;
#pragma unroll
        for (int i = 0; i < 4; ++i) {
            int off = base + (((i << 8) + t) << 2);
            float4 v = *(const float4*)(x + off);
            half4_t o;
            o.x = (_Float16)v.x; o.y = (_Float16)v.y;
            o.z = (_Float16)v.z; o.w = (_Float16)v.w;
            *(half4_t*)(xh + off) = o;
        }
    } else {
        // crossnet constants. beta_l = sum_{j<l} b_j; c_l = beta_l . w_l.
        __shared__ float redc[4][3];
        const int j = t << 2;
        float4 b0 = *(const float4*)(bs + 0 * H_SZ + j);
        float4 b1 = *(const float4*)(bs + 1 * H_SZ + j);
        float4 b2 = *(const float4*)(bs + 2 * H_SZ + j);
        float4 b3 = *(const float4*)(bs + 3 * H_SZ + j);
        float4 w1 = *(const float4*)(ws + 1 * H_SZ + j);
        float4 w2 = *(const float4*)(ws + 2 * H_SZ + j);
        float4 w3 = *(const float4*)(ws + 3 * H_SZ + j);
        float4 pre1 = b0;
        float4 pre2 = {pre1.x + b1.x, pre1.y + b1.y, pre1.z + b1.z, pre1.w + b1.w};
        float4 pre3 = {pre2.x + b2.x, pre2.y + b2.y, pre2.z + b2.z, pre2.w + b2.w};
        float4 bt   = {pre3.x + b3.x, pre3.y + b3.y, pre3.z + b3.z, pre3.w + b3.w};
        *(float4*)(beta4 + j) = bt;
        float pp[3];
        pp[0] = pre1.x * w1.x + pre1.y * w1.y + pre1.z * w1.z + pre1.w * w1.w;
        pp[1] = pre2.x * w2.x + pre2.y * w2.y + pre2.z * w2.z + pre2.w * w2.w;
        pp[2] = pre3.x * w3.x + pre3.y * w3.y + pre3.z * w3.z + pre3.w * w3.w;
#pragma unroll
        for (int off = 32; off > 0; off >>= 1) {
#pragma unroll
            for (int l = 0; l < 3; ++l) pp[l] += __shfl_down(pp[l], off, 64);
        }
        if ((t & 63) == 0) {
#pragma unroll
            for (int l = 0; l < 3; ++l) redc[t >> 6][l] = pp[l];
        }
        __syncthreads();
        if (t == 0) {
            cvec[0] = 0.0f;
#pragma unroll
            for (int l = 0; l < 3; ++l)
                cvec[l + 1] = redc[0][l] + redc[1][l] + redc[2][l] + redc[3][l];
        }
    }
}

// ---------------------------------------------------------------------------
// Kernel 2: GEMM h = xh @ Wt^T + b_enc. BM=32, BN=64, BK=128. 512 thr =
// 8 waves in 2(m) x 4(n), one 16x16 frag per wave. grid (16,32) = 512
// blocks = 2 blocks/CU. Double-buffered swizzled LDS (48 KB).
// ---------------------------------------------------------------------------
__global__ __launch_bounds__(512, 2) void gemm_kernel(
        const _Float16* __restrict__ xh, const _Float16* __restrict__ Wt,
        const float* __restrict__ b_enc, float* __restrict__ h) {
    // LDS rows of 128 halfs = 16 chunks of 16 B. Physical chunk (r,c) holds
    // logical k-chunk c ^ (r&15) -> fragment reads 2-way (free).
    __shared__ _Float16 As[2][32 * 128];   //  8 KB / buf
    __shared__ _Float16 Bs[2][64 * 128];   // 16 KB / buf
    const int tid  = threadIdx.x;
    const int lane = tid & 63;
    const int w    = tid >> 6;            // 0..7
    const int m0 = blockIdx.y << 5;
    const int n0 = blockIdx.x << 6;
    const int wm = (w >> 2) << 4;         // 0 / 16
    const int wn = (w & 3) << 4;          // 0 / 16 / 32 / 48

    // staging: A 512 slots (1/thread), B 1024 slots (2/thread).
    // slot s -> row r = s>>4, phys chunk s&15, logical chunk (s&15)^(r&15).
    const int ar = tid >> 4;                       // 0..31
    const int ac = ((tid & 15) ^ (ar & 15)) << 3;
    const int br0 = tid >> 4;                      // 0..31
    const int bc0 = ((tid & 15) ^ (br0 & 15)) << 3;
    const int br1 = br0 + 32;                      // 32..63
    const int bc1 = ((tid & 15) ^ (br1 & 15)) << 3;
    const _Float16* aSrc  = xh + (size_t)(m0 + ar) * D_SZ + ac;
    const _Float16* bSrc0 = Wt + (size_t)(n0 + br0) * D_SZ + bc0;
    const _Float16* bSrc1 = Wt + (size_t)(n0 + br1) * D_SZ + bc1;

    // fragment geometry (16x16x32): A[m=lane&15][k=q*8+j], B symmetric.
    const int ra = wm + (lane & 15);
    const int rb = wn + (lane & 15);
    const int q  = lane >> 4;

    floatx4_t acc = {0.0f, 0.0f, 0.0f, 0.0f};

    async_copy16(aSrc, &As[0][tid << 3]);
    async_copy16(bSrc0, &Bs[0][tid << 3]);
    async_copy16(bSrc1, &Bs[0][(tid + 512) << 3]);

    for (int it = 0; it < 8; ++it) {
        __syncthreads();   // drains stage(it); all waves done reading buf[(it+1)&1]
        if (it + 1 < 8) {
            int k0 = (it + 1) << 7;
            int buf = (it + 1) & 1;
            async_copy16(aSrc + k0, &As[buf][tid << 3]);
            async_copy16(bSrc0 + k0, &Bs[buf][tid << 3]);
            async_copy16(bSrc1 + k0, &Bs[buf][(tid + 512) << 3]);
        }
        const _Float16* Ab = As[it & 1];
        const _Float16* Bb = Bs[it & 1];
#pragma unroll
        for (int kk = 0; kk < 4; ++kk) {
            int l = (kk << 2) + q;
            half8_t af = *(const half8_t*)(Ab + ra * 128 + ((l ^ (ra & 15)) << 3));
            half8_t bf = *(const half8_t*)(Bb + rb * 128 + ((l ^ (rb & 15)) << 3));
            acc = __builtin_amdgcn_mfma_f32_16x16x32_f16(af, bf, acc, 0, 0, 0);
        }
    }

    // C/D: col = lane&15, row = (lane>>4)*4 + reg. b_enc folded in here.
    const int col  = n0 + wn + (lane & 15);
    const int row0 = m0 + wm + (q << 2);
    const float be = b_enc[col];
#pragma unroll
    for (int r = 0; r < 4; ++r)
        h[(size_t)(row0 + r) * H_SZ + col] = acc[r] + be;
}

// ---------------------------------------------------------------------------
// Kernel 3: CrossNet (affine-collapsed), one block per row, in-place.
//   x0 = h row (b_enc already folded); d_l = x0 . w_l (ONE reduction round);
//   sig: s_l = sig*d_l + c_l, sig += s_l; out = sig*x0 + beta4.
// ---------------------------------------------------------------------------
__global__ __launch_bounds__(256) void crossnet_kernel(
        float* __restrict__ h, const float* __restrict__ ws,
        const float* __restrict__ cvec, const float* __restrict__ beta4) {
    const int row = blockIdx.x;
    const int t = threadIdx.x;
    const int j = t << 2;
    float* hr = h + (size_t)row * H_SZ;

    float4 hv = *(const float4*)(hr + j);
    float x0[4] = {hv.x, hv.y, hv.z, hv.w};

    float p[DEPTH];
#pragma unroll
    for (int l = 0; l < DEPTH; ++l) {
        float4 wv = *(const float4*)(ws + l * H_SZ + j);
        p[l] = x0[0] * wv.x + x0[1] * wv.y + x0[2] * wv.z + x0[3] * wv.w;
    }
#pragma unroll
    for (int off = 32; off > 0; off >>= 1) {
#pragma unroll
        for (int l = 0; l < DEPTH; ++l) p[l] += __shfl_down(p[l], off, 64);
    }
    __shared__ float red[4][DEPTH];
    if ((t & 63) == 0) {
#pragma unroll
        for (int l = 0; l < DEPTH; ++l) red[t >> 6][l] = p[l];
    }
    __syncthreads();

    float sig = 1.0f;
#pragma unroll
    for (int l = 0; l < DEPTH; ++l) {
        float d = red[0][l] + red[1][l] + red[2][l] + red[3][l];
        float s = sig * d + cvec[l];
        sig += s;
    }
    float4 b4 = *(const float4*)(beta4 + j);
    float4 o = {x0[0] * sig + b4.x, x0[1] * sig + b4.y,
                x0[2] * sig + b4.z, x0[3] * sig + b4.w};
    *(float4*)(hr + j) = o;
}

extern "C" void kernel_launch(void* const* d_in, const int* in_sizes, int n_in,
                              void* d_out, int out_size, void* d_ws, size_t ws_size,
                              hipStream_t stream) {
    const float* x     = (const float*)d_in[0];
    const float* W_enc = (const float*)d_in[1];
    const float* b_enc = (const float*)d_in[2];
    const float* ws    = (const float*)d_in[3];
    const float* bs    = (const float*)d_in[4];
    float* out = (float*)d_out;

    _Float16* xh = (_Float16*)d_ws;                 // 2 MB
    _Float16* Wt = xh + (size_t)B_SZ * D_SZ;        // 2 MB
    float* aux   = (float*)((char*)d_ws + 4u * 1024u * 1024u);
    float* cvec  = aux;                             // 4 floats
    float* beta4 = aux + 4;                         // 1024 floats (16B-aligned)

    prep_kernel<<<513, 256, 0, stream>>>(x, W_enc, ws, bs, xh, Wt, cvec, beta4);
    dim3 grid(H_SZ / 64, B_SZ / 32);                // (n-tiles, m-tiles)
    gemm_kernel<<<grid, 512, 0, stream>>>(xh, Wt, b_enc, out);
    crossnet_kernel<<<B_SZ, 256, 0, stream>>>(out, ws, cvec, beta4);
}